// Round 17
// baseline (149.562 us; speedup 1.0000x reference)
//
#include <hip/hip_runtime.h>
#include <hip/hip_bf16.h>

// Blockwise 16x16 2D DCT (out = K @ T @ K^T), fp32 in/out, bf16 MFMA compute.
// R17 = R14's device code BYTE-IDENTICAL (correctness-proven) with R16's
// launch geometry: jobs_per_wave=2, 12288 address-ordered non-persistent
// blocks (copy-regime sliding window, proven by R15's 146us) + 2-job-deep
// register prefetch per wave (8 b128 loads in flight before compute).
// Per job: 4x b128 loads (16 full 64B lines each) -> cvt -> 4 MFMA ->
// lane-local transpose (D1 regs ARE B2 frags) -> 4 MFMA -> 16x b32 stores,
// each store instr covering 4 complete 64B lines. No LDS, no barriers.

#define IMG_W 1024

typedef float floatx4 __attribute__((ext_vector_type(4)));
typedef int   intx2   __attribute__((ext_vector_type(2)));

__device__ __forceinline__ int pk2(float a, float b) {
    __hip_bfloat16 ha = __float2bfloat16(a);
    __hip_bfloat16 hb = __float2bfloat16(b);
    unsigned short ua, ub;
    __builtin_memcpy(&ua, &ha, 2);
    __builtin_memcpy(&ub, &hb, 2);
    return (int)((unsigned)ua | ((unsigned)ub << 16));
}

#define MFMA16(D, A, B, C)                                        \
    asm volatile("v_mfma_f32_16x16x16_bf16 %0, %1, %2, %3"        \
                 : "=&v"(D) : "v"(A), "v"(B), "v"(C))

__global__ __launch_bounds__(256) void dct16_kernel(
    const float* __restrict__ x,
    const float* __restrict__ kern,      // 16x16 DCT matrix, row-major fp32
    float* __restrict__ out,
    int jobs_per_wave, int total_jobs)
{
    const int tid  = threadIdx.x;
    const int lane = tid & 63;
    const int wid  = tid >> 6;
    const int li   = lane & 15;          // matrix row/col index
    const int g    = lane >> 4;          // k-group 0..3

    // constant fragment: lane holds K[li][4g..4g+3] as bf16 pairs.
    // Serves as B1 (=K^T: B[k][c]=K[c][k], c=li) and A2 (=K: A[i][k], i=li).
    intx2 KF;
    {
        floatx4 kv = *reinterpret_cast<const floatx4*>(kern + li * 16 + 4 * g);
        KF.x = pk2(kv[0], kv[1]);
        KF.y = pk2(kv[2], kv[3]);
    }

    const int gw = blockIdx.x * 4 + wid;     // global wave id
    int j0 = gw * jobs_per_wave;
    if (j0 >= total_jobs) return;            // no barriers -> safe
    int nj = jobs_per_wave;
    if (j0 + nj > total_jobs) nj = total_jobs - j0;

    // job j: 16 rows x 64 cols. band = j>>4, col64 = j&15.
    auto jbase = [](int j) -> size_t {
        return (size_t)(j >> 4) * (16 * IMG_W) + (size_t)(j & 15) * 64;
    };

    floatx4 preA[4], preB[4];                // 2-job-deep prefetch
    auto load_job = [&](int j, floatx4 (&pre)[4]) {
        const float* gp = x + jbase(j) + (size_t)li * IMG_W + 4 * g;
        #pragma unroll
        for (int tt = 0; tt < 4; ++tt)       // tile tt: cols 16tt..16tt+15
            pre[tt] = *reinterpret_cast<const floatx4*>(gp + tt * 16);
    };

    const floatx4 z = {0.f, 0.f, 0.f, 0.f};

    auto run_job = [&](floatx4 (&pre)[4], int j, int jpref) {
        // cvt A1 frags (consumes pre; compiler inserts the vmcnt wait here)
        intx2 A0, A1, A2t, A3;
        A0.x  = pk2(pre[0][0], pre[0][1]);  A0.y  = pk2(pre[0][2], pre[0][3]);
        A1.x  = pk2(pre[1][0], pre[1][1]);  A1.y  = pk2(pre[1][2], pre[1][3]);
        A2t.x = pk2(pre[2][0], pre[2][1]);  A2t.y = pk2(pre[2][2], pre[2][3]);
        A3.x  = pk2(pre[3][0], pre[3][1]);  A3.y  = pk2(pre[3][2], pre[3][3]);
        if (jpref >= 0) load_job(jpref, pre);    // refill (unused at nj=2)

        // pass 1: V = T * K^T
        __builtin_amdgcn_sched_barrier(0);
        asm volatile("s_nop 1");
        floatx4 V0, V1, V2, V3;
        MFMA16(V0, A0,  KF, z);
        MFMA16(V1, A1,  KF, z);
        MFMA16(V2, A2t, KF, z);
        MFMA16(V3, A3,  KF, z);
        asm volatile("s_nop 7\n\ts_nop 7");
        __builtin_amdgcn_sched_barrier(0);

        // lane-local transpose: D1 regs (V rows 4g+r) are B2 elements (k=4g+j)
        intx2 B0, B1, B2, B3;
        B0.x = pk2(V0[0], V0[1]);  B0.y = pk2(V0[2], V0[3]);
        B1.x = pk2(V1[0], V1[1]);  B1.y = pk2(V1[2], V1[3]);
        B2.x = pk2(V2[0], V2[1]);  B2.y = pk2(V2[2], V2[3]);
        B3.x = pk2(V3[0], V3[1]);  B3.y = pk2(V3[2], V3[3]);

        // pass 2: O = K * V
        __builtin_amdgcn_sched_barrier(0);
        asm volatile("s_nop 1");
        floatx4 O0, O1, O2, O3;
        MFMA16(O0, KF, B0, z);
        MFMA16(O1, KF, B1, z);
        MFMA16(O2, KF, B2, z);
        MFMA16(O3, KF, B3, z);
        asm volatile("s_nop 7\n\ts_nop 7");
        __builtin_amdgcn_sched_barrier(0);

        // direct store: instr (r, tt) writes 4 complete 64B lines (one per g):
        // out[base + (4g+r)*W + tt*16 + li], 16 lanes x 4B contiguous per line.
        float* gout = out + jbase(j) + (size_t)(4 * g) * IMG_W + li;
        #pragma unroll
        for (int r = 0; r < 4; ++r) {
            gout[(size_t)r * IMG_W +  0] = O0[r];
            gout[(size_t)r * IMG_W + 16] = O1[r];
            gout[(size_t)r * IMG_W + 32] = O2[r];
            gout[(size_t)r * IMG_W + 48] = O3[r];
        }
    };

    // prologue: 2 jobs in flight
    load_job(j0, preA);
    if (nj > 1) load_job(j0 + 1, preB);

    int k = 0;
    for (; k + 1 < nj; k += 2) {
        run_job(preA, j0 + k,     (k + 2 < nj) ? j0 + k + 2 : -1);
        run_job(preB, j0 + k + 1, (k + 3 < nj) ? j0 + k + 3 : -1);
    }
    if (k < nj) run_job(preA, j0 + k, -1);
}

extern "C" void kernel_launch(void* const* d_in, const int* in_sizes, int n_in,
                              void* d_out, int out_size, void* d_ws, size_t ws_size,
                              hipStream_t stream) {
    const float* x    = (const float*)d_in[0];
    const float* kern = (const float*)d_in[1];
    float* out        = (float*)d_out;

    const int n_img      = in_sizes[0] / (IMG_W * IMG_W);     // 96
    const int total_jobs = n_img * 64 * 16;                   // 98304 jobs of 16x64
    const int per_wave   = 2;                                 // 2-job pipeline
    const int n_waves    = (total_jobs + per_wave - 1) / per_wave;
    const int blocks     = (n_waves + 3) / 4;                 // 12288, address order

    dct16_kernel<<<blocks, 256, 0, stream>>>(x, kern, out, per_wave, total_jobs);
}

// Round 18
// 146.376 us; speedup vs baseline: 1.0218x; 1.0218x over previous
//
#include <hip/hip_runtime.h>
#include <hip/hip_bf16.h>

// Blockwise 16x16 2D DCT (out = K @ T @ K^T), fp32 in/out, bf16 MFMA compute.
// R18 = R15 byte-identical (best measured: 146.0us) — final configuration.
// COPY-REGIME DISPATCH: non-persistent, 24576 address-ordered blocks x 256 thr;
// block b = strip b (4 waves x one 16x64 job). Resident blocks form a sliding
// contiguous window over memory (fill/copy regime). Per wave: 4x b128 loads
// (16 full 64B lines each) -> cvt -> 4 MFMA (V=T*K^T) -> lane-local transpose
// (D1 regs ARE B2 frags) -> 4 MFMA (O=K*V) -> 16 stores, each covering 4
// complete 64B lines. No LDS, no barriers, no loop.
// A/B history: persistent variants 167-254us; staged stores, NT hints,
// 2-job depth (R17: 149.6us), barrier-free wave-local LDS all null/worse.

#define IMG_W 1024

typedef float floatx4 __attribute__((ext_vector_type(4)));
typedef int   intx2   __attribute__((ext_vector_type(2)));

__device__ __forceinline__ int pk2(float a, float b) {
    __hip_bfloat16 ha = __float2bfloat16(a);
    __hip_bfloat16 hb = __float2bfloat16(b);
    unsigned short ua, ub;
    __builtin_memcpy(&ua, &ha, 2);
    __builtin_memcpy(&ub, &hb, 2);
    return (int)((unsigned)ua | ((unsigned)ub << 16));
}

#define MFMA16(D, A, B, C)                                        \
    asm volatile("v_mfma_f32_16x16x16_bf16 %0, %1, %2, %3"        \
                 : "=&v"(D) : "v"(A), "v"(B), "v"(C))

__global__ __launch_bounds__(256) void dct16_kernel(
    const float* __restrict__ x,
    const float* __restrict__ kern,      // 16x16 DCT matrix, row-major fp32
    float* __restrict__ out,
    int total_jobs)
{
    const int tid  = threadIdx.x;
    const int lane = tid & 63;
    const int wid  = tid >> 6;
    const int li   = lane & 15;          // matrix row/col index
    const int g    = lane >> 4;          // k-group 0..3

    const int j = blockIdx.x * 4 + wid;  // job id, address order
    if (j >= total_jobs) return;

    // constant fragment: lane holds K[li][4g..4g+3] as bf16 pairs.
    // Serves as B1 (=K^T: B[k][c]=K[c][k], c=li) and A2 (=K: A[i][k], i=li).
    intx2 KF;
    {
        floatx4 kv = *reinterpret_cast<const floatx4*>(kern + li * 16 + 4 * g);
        KF.x = pk2(kv[0], kv[1]);
        KF.y = pk2(kv[2], kv[3]);
    }

    // job j: 16 rows x 64 cols. band = j>>4, col64 = j&15.
    const size_t base = (size_t)(j >> 4) * (16 * IMG_W) + (size_t)(j & 15) * 64;

    // load: tile tt -> lane reads T[li][16tt + 4g .. +3]; one instr = 16 full lines
    const float* gp = x + base + (size_t)li * IMG_W + 4 * g;
    floatx4 pre[4];
    #pragma unroll
    for (int tt = 0; tt < 4; ++tt)
        pre[tt] = *reinterpret_cast<const floatx4*>(gp + tt * 16);

    const floatx4 z = {0.f, 0.f, 0.f, 0.f};

    // cvt A1 frags (vmcnt wait inserted here by compiler)
    intx2 A0, A1, A2t, A3;
    A0.x  = pk2(pre[0][0], pre[0][1]);  A0.y  = pk2(pre[0][2], pre[0][3]);
    A1.x  = pk2(pre[1][0], pre[1][1]);  A1.y  = pk2(pre[1][2], pre[1][3]);
    A2t.x = pk2(pre[2][0], pre[2][1]);  A2t.y = pk2(pre[2][2], pre[2][3]);
    A3.x  = pk2(pre[3][0], pre[3][1]);  A3.y  = pk2(pre[3][2], pre[3][3]);

    // pass 1: V = T * K^T
    __builtin_amdgcn_sched_barrier(0);
    asm volatile("s_nop 1");
    floatx4 V0, V1, V2, V3;
    MFMA16(V0, A0,  KF, z);
    MFMA16(V1, A1,  KF, z);
    MFMA16(V2, A2t, KF, z);
    MFMA16(V3, A3,  KF, z);
    asm volatile("s_nop 7\n\ts_nop 7");
    __builtin_amdgcn_sched_barrier(0);

    // lane-local transpose: D1 regs (V rows 4g+r) are B2 elements (k=4g+j)
    intx2 B0, B1, B2, B3;
    B0.x = pk2(V0[0], V0[1]);  B0.y = pk2(V0[2], V0[3]);
    B1.x = pk2(V1[0], V1[1]);  B1.y = pk2(V1[2], V1[3]);
    B2.x = pk2(V2[0], V2[1]);  B2.y = pk2(V2[2], V2[3]);
    B3.x = pk2(V3[0], V3[1]);  B3.y = pk2(V3[2], V3[3]);

    // pass 2: O = K * V
    __builtin_amdgcn_sched_barrier(0);
    asm volatile("s_nop 1");
    floatx4 O0, O1, O2, O3;
    MFMA16(O0, KF, B0, z);
    MFMA16(O1, KF, B1, z);
    MFMA16(O2, KF, B2, z);
    MFMA16(O3, KF, B3, z);
    asm volatile("s_nop 7\n\ts_nop 7");
    __builtin_amdgcn_sched_barrier(0);

    // store: instr (r, tt) writes 4 complete 64B lines (one per g):
    // out[base + (4g+r)*W + tt*16 + li], 16 lanes x 4B contiguous per line.
    float* gout = out + base + (size_t)(4 * g) * IMG_W + li;
    #pragma unroll
    for (int r = 0; r < 4; ++r) {
        gout[(size_t)r * IMG_W +  0] = O0[r];
        gout[(size_t)r * IMG_W + 16] = O1[r];
        gout[(size_t)r * IMG_W + 32] = O2[r];
        gout[(size_t)r * IMG_W + 48] = O3[r];
    }
}

extern "C" void kernel_launch(void* const* d_in, const int* in_sizes, int n_in,
                              void* d_out, int out_size, void* d_ws, size_t ws_size,
                              hipStream_t stream) {
    const float* x    = (const float*)d_in[0];
    const float* kern = (const float*)d_in[1];
    float* out        = (float*)d_out;

    const int n_img      = in_sizes[0] / (IMG_W * IMG_W);     // 96
    const int total_jobs = n_img * 64 * 16;                   // 98304 jobs of 16x64
    const int blocks     = (total_jobs + 3) / 4;              // 24576, address order

    dct16_kernel<<<blocks, 256, 0, stream>>>(x, kern, out, total_jobs);
}